// Round 1
// baseline (963.432 us; speedup 1.0000x reference)
//
#include <hip/hip_runtime.h>
#include <hip/hip_bf16.h>

#define N_NODES 10000
#define N_EDGES 160000
#define D_H 512
#define BN_EPS 1e-5f
#define LEAKY_SLOPE 0.2f

// ---------------- graph preprocessing ----------------

__global__ void k_init(float* deg, int* counts) {
    int i = blockIdx.x * blockDim.x + threadIdx.x;
    if (i < N_NODES) { deg[i] = 1.0f; counts[i] = 0; }  // 1.0 = self-loop
}

__global__ void k_count(const int* __restrict__ ei, float* deg, int* counts) {
    int e = blockIdx.x * blockDim.x + threadIdx.x;
    if (e < N_EDGES) {
        int dst = ei[N_EDGES + e];
        atomicAdd(&deg[dst], 1.0f);
        atomicAdd(&counts[dst], 1);
    }
}

__global__ void k_dinv(float* deg) {
    int i = blockIdx.x * blockDim.x + threadIdx.x;
    if (i < N_NODES) deg[i] = rsqrtf(deg[i]);   // deg >= 1 always (self-loop)
}

// single-block exclusive scan of counts[N] -> rowptr[N+1], cursor copy
__global__ __launch_bounds__(1024) void k_scan(const int* __restrict__ counts,
                                               int* rowptr, int* cursor) {
    __shared__ int sums[1024];
    int t = threadIdx.x;
    int vals[10];
    int base = t * 10;                 // 1024*10 >= 10000
    int s = 0;
    #pragma unroll
    for (int j = 0; j < 10; j++) {
        int idx = base + j;
        int v = (idx < N_NODES) ? counts[idx] : 0;
        vals[j] = v; s += v;
    }
    sums[t] = s;
    __syncthreads();
    for (int off = 1; off < 1024; off <<= 1) {
        int v = (t >= off) ? sums[t - off] : 0;
        __syncthreads();
        if (t >= off) sums[t] += v;
        __syncthreads();
    }
    int excl = (t == 0) ? 0 : sums[t - 1];
    #pragma unroll
    for (int j = 0; j < 10; j++) {
        int idx = base + j;
        if (idx < N_NODES) { rowptr[idx] = excl; cursor[idx] = excl; excl += vals[j]; }
    }
    if (t == 1023) rowptr[N_NODES] = sums[1023];
}

__global__ void k_fill(const int* __restrict__ ei, int* cursor, int* colidx) {
    int e = blockIdx.x * blockDim.x + threadIdx.x;
    if (e < N_EDGES) {
        int src = ei[e];
        int dst = ei[N_EDGES + e];
        int p = atomicAdd(&cursor[dst], 1);
        colidx[p] = src;
    }
}

// ---------------- GEMM: C[N x 512] = A[N x K] @ W[K x 512] (+bias) ----------------
// 64x64 tile, 256 threads, 4x4 micro-tile, K-tile 16.

__global__ __launch_bounds__(256) void k_gemm(const float* __restrict__ A,
        const float* __restrict__ W, const float* __restrict__ bias,
        float* __restrict__ C, int K) {
    __shared__ float As[16][64];
    __shared__ float Bs[16][64];
    int tid = threadIdx.x;
    int row0 = blockIdx.y * 64;
    int col0 = blockIdx.x * 64;
    int tr = tid >> 4, tc = tid & 15;
    int la_r = tid >> 2;            // 0..63
    int la_k = (tid & 3) << 2;      // 0,4,8,12
    int lb_k = tid >> 4;            // 0..15
    int lb_m = (tid & 15) << 2;     // 0..60
    float acc[4][4] = {};
    for (int k0 = 0; k0 < K; k0 += 16) {
        int ar = row0 + la_r;
        float4 av = make_float4(0.f, 0.f, 0.f, 0.f);
        if (ar < N_NODES) av = *reinterpret_cast<const float4*>(A + (size_t)ar * K + k0 + la_k);
        As[la_k + 0][la_r] = av.x;
        As[la_k + 1][la_r] = av.y;
        As[la_k + 2][la_r] = av.z;
        As[la_k + 3][la_r] = av.w;
        float4 bv = *reinterpret_cast<const float4*>(W + (size_t)(k0 + lb_k) * D_H + col0 + lb_m);
        *reinterpret_cast<float4*>(&Bs[lb_k][lb_m]) = bv;
        __syncthreads();
        #pragma unroll
        for (int kk = 0; kk < 16; kk++) {
            float a[4], b[4];
            #pragma unroll
            for (int i = 0; i < 4; i++) a[i] = As[kk][tr * 4 + i];
            #pragma unroll
            for (int j = 0; j < 4; j++) b[j] = Bs[kk][tc * 4 + j];
            #pragma unroll
            for (int i = 0; i < 4; i++)
                #pragma unroll
                for (int j = 0; j < 4; j++)
                    acc[i][j] += a[i] * b[j];
        }
        __syncthreads();
    }
    #pragma unroll
    for (int i = 0; i < 4; i++) {
        int r = row0 + tr * 4 + i;
        if (r < N_NODES) {
            #pragma unroll
            for (int j = 0; j < 4; j++) {
                int c = col0 + tc * 4 + j;
                float v = acc[i][j];
                if (bias) v += bias[c];
                C[(size_t)r * D_H + c] = v;
            }
        }
    }
}

// ---------------- aggregation: out[i] = dinv[i]*(sum_nbr dinv[s]*tmp[s] + dinv[i]*tmp[i]) + b ----------------

__global__ __launch_bounds__(512) void k_aggregate(const float* __restrict__ tmp,
        const int* __restrict__ rowptr, const int* __restrict__ colidx,
        const float* __restrict__ dinv, const float* __restrict__ bias,
        float* __restrict__ out, int relu) {
    int i = blockIdx.x;
    int f = threadIdx.x;
    float di = dinv[i];
    float s = di * tmp[(size_t)i * D_H + f];   // self-loop term (norm = di*di)
    int beg = rowptr[i], end = rowptr[i + 1];
    for (int e = beg; e < end; e++) {
        int src = colidx[e];
        s += dinv[src] * tmp[(size_t)src * D_H + f];
    }
    float v = di * s + bias[f];
    if (relu) v = (v >= 0.f) ? v : LEAKY_SLOPE * v;
    out[(size_t)i * D_H + f] = v;
}

// ---------------- batch norm ----------------

__global__ void k_zero1024(float* p) {
    int i = blockIdx.x * blockDim.x + threadIdx.x;
    if (i < 2 * D_H) p[i] = 0.f;
}

__global__ __launch_bounds__(256) void k_bnstats(const float* __restrict__ h,
        float* musum, float* varsum) {
    int r0 = blockIdx.x * 100;       // 100 blocks x 100 rows
    int t = threadIdx.x;
    int c0 = t, c1 = t + 256;
    float s0 = 0.f, s1 = 0.f, q0 = 0.f, q1 = 0.f;
    for (int r = r0; r < r0 + 100; r++) {
        float v0 = h[(size_t)r * D_H + c0];
        float v1 = h[(size_t)r * D_H + c1];
        s0 += v0; q0 += v0 * v0;
        s1 += v1; q1 += v1 * v1;
    }
    atomicAdd(&musum[c0], s0); atomicAdd(&varsum[c0], q0);
    atomicAdd(&musum[c1], s1); atomicAdd(&varsum[c1], q1);
}

__global__ void k_bnfin(const float* musum, const float* varsum,
        const float* __restrict__ g, const float* __restrict__ beta,
        float* scale, float* shift) {
    int c = blockIdx.x * blockDim.x + threadIdx.x;
    if (c < D_H) {
        float mu = musum[c] * (1.0f / N_NODES);
        float var = varsum[c] * (1.0f / N_NODES) - mu * mu;
        float rs = rsqrtf(var + BN_EPS);
        float sc = rs * g[c];
        scale[c] = sc;
        shift[c] = beta[c] - mu * sc;
    }
}

__global__ void k_bnapply(float* h, const float* __restrict__ scale,
        const float* __restrict__ shift) {
    int idx = blockIdx.x * blockDim.x + threadIdx.x;   // N*512 total
    int c = idx & (D_H - 1);
    h[idx] = h[idx] * scale[c] + shift[c];
}

// ---------------- launch ----------------

extern "C" void kernel_launch(void* const* d_in, const int* in_sizes, int n_in,
                              void* d_out, int out_size, void* d_ws, size_t ws_size,
                              hipStream_t stream) {
    (void)in_sizes; (void)n_in; (void)out_size; (void)ws_size;
    const float* x  = (const float*)d_in[0];
    const int*   ei = (const int*)d_in[1];
    const float *W[5], *bb[5], *gg[5], *beb[5];
    for (int i = 0; i < 5; i++) {
        W[i]   = (const float*)d_in[2 + 4 * i];
        bb[i]  = (const float*)d_in[3 + 4 * i];
        gg[i]  = (const float*)d_in[4 + 4 * i];
        beb[i] = (const float*)d_in[5 + 4 * i];
    }
    const float* Wf = (const float*)d_in[22];
    const float* bf = (const float*)d_in[23];
    float* out = (float*)d_out;

    // workspace layout (~42 MB)
    float* h      = (float*)d_ws;
    float* tmp    = h + (size_t)N_NODES * D_H;
    float* dinv   = tmp + (size_t)N_NODES * D_H;
    float* musum  = dinv + N_NODES;
    float* varsum = musum + D_H;
    float* scale  = varsum + D_H;
    float* shift  = scale + D_H;
    int* counts   = (int*)(shift + D_H);
    int* rowptr   = counts + N_NODES;
    int* cursor   = rowptr + N_NODES + 1;
    int* colidx   = cursor + N_NODES;

    k_init<<<(N_NODES + 255) / 256, 256, 0, stream>>>(dinv, counts);
    k_count<<<(N_EDGES + 255) / 256, 256, 0, stream>>>(ei, dinv, counts);
    k_dinv<<<(N_NODES + 255) / 256, 256, 0, stream>>>(dinv);
    k_scan<<<1, 1024, 0, stream>>>(counts, rowptr, cursor);
    k_fill<<<(N_EDGES + 255) / 256, 256, 0, stream>>>(ei, cursor, colidx);

    dim3 ggrid(D_H / 64, (N_NODES + 63) / 64);
    const float* hin = x;
    for (int l = 0; l < 5; l++) {
        int K = (l == 0) ? 256 : 512;
        k_gemm<<<ggrid, 256, 0, stream>>>(hin, W[l], nullptr, tmp, K);
        k_aggregate<<<N_NODES, 512, 0, stream>>>(tmp, rowptr, colidx, dinv, bb[l], h, (l < 4) ? 1 : 0);
        k_zero1024<<<4, 256, 0, stream>>>(musum);   // zeros musum+varsum (contiguous)
        k_bnstats<<<100, 256, 0, stream>>>(h, musum, varsum);
        k_bnfin<<<2, 256, 0, stream>>>(musum, varsum, gg[l], beb[l], scale, shift);
        k_bnapply<<<(N_NODES * D_H) / 256, 256, 0, stream>>>(h, scale, shift);
        hin = h;
    }
    k_gemm<<<ggrid, 256, 0, stream>>>(h, Wf, bf, out, 512);
}

// Round 2
// 409.641 us; speedup vs baseline: 2.3519x; 2.3519x over previous
//
#include <hip/hip_runtime.h>
#include <hip/hip_bf16.h>

#define N_NODES 10000
#define N_PAD   10112          // 79 * 128
#define N_EDGES 160000
#define D_H 512
#define BN_EPS 1e-5f
#define LEAKY_SLOPE 0.2f

typedef __attribute__((ext_vector_type(8))) __bf16 bf16x8;
typedef __attribute__((ext_vector_type(4))) float f32x4;

// ---------------- graph preprocessing ----------------

__global__ void k_init(float* deg, int* counts) {
    int i = blockIdx.x * blockDim.x + threadIdx.x;
    if (i < N_NODES) { deg[i] = 1.0f; counts[i] = 0; }  // 1.0 = self-loop
}

__global__ void k_count(const int* __restrict__ ei, float* deg, int* counts) {
    int e = blockIdx.x * blockDim.x + threadIdx.x;
    if (e < N_EDGES) {
        int dst = ei[N_EDGES + e];
        atomicAdd(&deg[dst], 1.0f);
        atomicAdd(&counts[dst], 1);
    }
}

__global__ void k_dinv(float* deg) {
    int i = blockIdx.x * blockDim.x + threadIdx.x;
    if (i < N_NODES) deg[i] = rsqrtf(deg[i]);
}

__global__ __launch_bounds__(1024) void k_scan(const int* __restrict__ counts,
                                               int* rowptr, int* cursor) {
    __shared__ int sums[1024];
    int t = threadIdx.x;
    int vals[10];
    int base = t * 10;
    int s = 0;
    #pragma unroll
    for (int j = 0; j < 10; j++) {
        int idx = base + j;
        int v = (idx < N_NODES) ? counts[idx] : 0;
        vals[j] = v; s += v;
    }
    sums[t] = s;
    __syncthreads();
    for (int off = 1; off < 1024; off <<= 1) {
        int v = (t >= off) ? sums[t - off] : 0;
        __syncthreads();
        if (t >= off) sums[t] += v;
        __syncthreads();
    }
    int excl = (t == 0) ? 0 : sums[t - 1];
    #pragma unroll
    for (int j = 0; j < 10; j++) {
        int idx = base + j;
        if (idx < N_NODES) { rowptr[idx] = excl; cursor[idx] = excl; excl += vals[j]; }
    }
    if (t == 1023) rowptr[N_NODES] = sums[1023];
}

__global__ void k_fill(const int* __restrict__ ei, int* cursor, int* colidx) {
    int e = blockIdx.x * blockDim.x + threadIdx.x;
    if (e < N_EDGES) {
        int src = ei[e];
        int dst = ei[N_EDGES + e];
        int p = atomicAdd(&cursor[dst], 1);
        colidx[p] = src;
    }
}

// ---------------- weight convert + transpose: W[di][512] f32 -> Wt[512][di] bf16 ----

struct WtDesc { const float* w; __hip_bfloat16* wt; int di; };
struct WtPack { WtDesc d[6]; };

__global__ __launch_bounds__(256) void k_wt(WtPack p) {
    WtDesc d = p.d[blockIdx.z];
    int r0 = blockIdx.x * 32;             // row tile in W (di dim)
    if (r0 >= d.di) return;
    int c0 = blockIdx.y * 32;             // col tile in W (do dim = 512)
    __shared__ float t[32][33];
    int tx = threadIdx.x & 31, ty = threadIdx.x >> 5;   // 32 x 8
    for (int rr = ty; rr < 32; rr += 8)
        t[rr][tx] = d.w[(size_t)(r0 + rr) * 512 + c0 + tx];
    __syncthreads();
    for (int rr = ty; rr < 32; rr += 8)
        d.wt[(size_t)(c0 + rr) * d.di + r0 + tx] = __float2bfloat16(t[tx][rr]);
}

// ---------------- x convert: f32 [10000][256] -> bf16 ----------------

__global__ __launch_bounds__(256) void k_xcvt(const float* __restrict__ x,
                                              __hip_bfloat16* __restrict__ hb) {
    int i = blockIdx.x * 256 + threadIdx.x;   // 320000 lanes, 8 els each
    size_t base = (size_t)i * 8;
    float4 a = *reinterpret_cast<const float4*>(x + base);
    float4 b = *reinterpret_cast<const float4*>(x + base + 4);
    bf16x8 o;
    o[0] = (__bf16)a.x; o[1] = (__bf16)a.y; o[2] = (__bf16)a.z; o[3] = (__bf16)a.w;
    o[4] = (__bf16)b.x; o[5] = (__bf16)b.y; o[6] = (__bf16)b.z; o[7] = (__bf16)b.w;
    *reinterpret_cast<bf16x8*>((unsigned short*)hb + base) = o;
}

// ---------------- bf16 MFMA GEMM: C[M x 512] = A[Mpad x K] @ Wt[512 x K]^T ----------
// 128x128 tile, 256 threads (4 waves 2x2), 16x16x32 MFMA, BK=32, global_load_lds.

__device__ __forceinline__ void gload16(const void* g, void* l) {
    __builtin_amdgcn_global_load_lds(
        (const __attribute__((address_space(1))) void*)g,
        (__attribute__((address_space(3))) void*)l, 16, 0, 0);
}

template<int OUT_BF16>
__global__ __launch_bounds__(256) void k_gemm_mfma(
        const __hip_bfloat16* __restrict__ A,    // [N_PAD x K] row-major
        const __hip_bfloat16* __restrict__ Bt,   // [512 x K] row-major
        const float* __restrict__ bias,          // only for f32 path
        __hip_bfloat16* __restrict__ Cb, float* __restrict__ Cf,
        int K) {
    __shared__ alignas(16) __hip_bfloat16 As[128][32];
    __shared__ alignas(16) __hip_bfloat16 Bs[128][32];
    int tid = threadIdx.x;
    int lane = tid & 63;
    int w = tid >> 6;
    int wm = w >> 1, wn = w & 1;          // wave tile 64x64
    int row0 = blockIdx.y * 128;
    int col0 = blockIdx.x * 128;
    int sr = lane >> 2;                   // staging row within 16-row chunk
    int sk = (lane & 3) * 8;              // staging k offset
    int fl = lane & 15;                   // fragment row/col
    int fk = (lane >> 4) * 8;             // fragment k offset

    f32x4 acc[4][4] = {};

    for (int k0 = 0; k0 < K; k0 += 32) {
        #pragma unroll
        for (int it = 0; it < 2; ++it) {
            int c = w + it * 4;           // chunk 0..7 (16 rows each)
            gload16(A  + (size_t)(row0 + c * 16 + sr) * K + k0 + sk, &As[c * 16][0]);
            gload16(Bt + (size_t)(col0 + c * 16 + sr) * K + k0 + sk, &Bs[c * 16][0]);
        }
        __syncthreads();
        bf16x8 af[4], bfr[4];
        #pragma unroll
        for (int i = 0; i < 4; ++i) {
            af[i]  = *reinterpret_cast<const bf16x8*>(&As[wm * 64 + i * 16 + fl][fk]);
            bfr[i] = *reinterpret_cast<const bf16x8*>(&Bs[wn * 64 + i * 16 + fl][fk]);
        }
        #pragma unroll
        for (int i = 0; i < 4; ++i)
            #pragma unroll
            for (int j = 0; j < 4; ++j)
                acc[i][j] = __builtin_amdgcn_mfma_f32_16x16x32_bf16(af[i], bfr[j], acc[i][j], 0, 0, 0);
        __syncthreads();
    }

    int rg = (lane >> 4) * 4;             // C/D: col=lane&15, row=(lane>>4)*4+reg
    #pragma unroll
    for (int i = 0; i < 4; ++i) {
        #pragma unroll
        for (int j = 0; j < 4; ++j) {
            int col = col0 + wn * 64 + j * 16 + fl;
            #pragma unroll
            for (int r = 0; r < 4; ++r) {
                int row = row0 + wm * 64 + i * 16 + rg + r;
                if (row < N_NODES) {
                    float v = acc[i][j][r];
                    if (OUT_BF16) {
                        Cb[(size_t)row * D_H + col] = __float2bfloat16(v);
                    } else {
                        Cf[(size_t)row * D_H + col] = v + bias[col];
                    }
                }
            }
        }
    }
}

// ---------------- aggregation (bf16 in/out, fp32 accum) ----------------
// out[i] = leaky( dinv[i]*(sum_nbr dinv[s]*tmp[s] + dinv[i]*tmp[i]) + b )

__global__ __launch_bounds__(256) void k_aggregate(const __hip_bfloat16* __restrict__ tmp,
        const int* __restrict__ rowptr, const int* __restrict__ colidx,
        const float* __restrict__ dinv, const float* __restrict__ bias,
        __hip_bfloat16* __restrict__ out, int relu) {
    int node = blockIdx.x * 4 + (threadIdx.x >> 6);
    int lane = threadIdx.x & 63;
    float di = dinv[node];
    bf16x8 v = *reinterpret_cast<const bf16x8*>(tmp + (size_t)node * D_H + lane * 8);
    float s[8];
    #pragma unroll
    for (int j = 0; j < 8; j++) s[j] = di * (float)v[j];
    int beg = rowptr[node], end = rowptr[node + 1];
    for (int e = beg; e < end; e++) {
        int src = colidx[e];
        float ds = dinv[src];
        bf16x8 u = *reinterpret_cast<const bf16x8*>(tmp + (size_t)src * D_H + lane * 8);
        #pragma unroll
        for (int j = 0; j < 8; j++) s[j] += ds * (float)u[j];
    }
    bf16x8 o;
    #pragma unroll
    for (int j = 0; j < 8; j++) {
        float val = di * s[j] + bias[lane * 8 + j];
        if (relu) val = (val >= 0.f) ? val : LEAKY_SLOPE * val;
        o[j] = (__bf16)val;
    }
    *reinterpret_cast<bf16x8*>(out + (size_t)node * D_H + lane * 8) = o;
}

// ---------------- batch norm ----------------

__global__ void k_zero(float* p) { p[threadIdx.x] = 0.f; }   // 1024 threads: musum+varsum

__global__ __launch_bounds__(256) void k_bnstats(const __hip_bfloat16* __restrict__ h,
        float* musum, float* varsum) {
    int r0 = blockIdx.x * 100;
    int t = threadIdx.x;
    int c0 = t, c1 = t + 256;
    float s0 = 0.f, s1 = 0.f, q0 = 0.f, q1 = 0.f;
    for (int r = r0; r < r0 + 100; r++) {
        float v0 = __bfloat162float(h[(size_t)r * D_H + c0]);
        float v1 = __bfloat162float(h[(size_t)r * D_H + c1]);
        s0 += v0; q0 += v0 * v0;
        s1 += v1; q1 += v1 * v1;
    }
    atomicAdd(&musum[c0], s0); atomicAdd(&varsum[c0], q0);
    atomicAdd(&musum[c1], s1); atomicAdd(&varsum[c1], q1);
}

__global__ __launch_bounds__(256) void k_bnapply(const __hip_bfloat16* __restrict__ hin,
        const float* __restrict__ musum, const float* __restrict__ varsum,
        const float* __restrict__ g, const float* __restrict__ beta,
        __hip_bfloat16* __restrict__ hout) {
    int i = blockIdx.x * 256 + threadIdx.x;     // 640000 lanes
    int cg = (i & 63) * 8;
    size_t off = (size_t)(i >> 6) * D_H + cg;
    bf16x8 v = *reinterpret_cast<const bf16x8*>(hin + off);
    bf16x8 o;
    #pragma unroll
    for (int j = 0; j < 8; j++) {
        int c = cg + j;
        float mu = musum[c] * (1.0f / N_NODES);
        float var = varsum[c] * (1.0f / N_NODES) - mu * mu;
        float sc = rsqrtf(var + BN_EPS) * g[c];
        o[j] = (__bf16)(__bfloat162float(v[j]) * sc + (beta[c] - mu * sc));
    }
    *reinterpret_cast<bf16x8*>(hout + off) = o;
}

// ---------------- launch ----------------

extern "C" void kernel_launch(void* const* d_in, const int* in_sizes, int n_in,
                              void* d_out, int out_size, void* d_ws, size_t ws_size,
                              hipStream_t stream) {
    (void)in_sizes; (void)n_in; (void)out_size; (void)ws_size;
    const float* x  = (const float*)d_in[0];
    const int*   ei = (const int*)d_in[1];
    const float *W[6], *bb[5], *gg[5], *beb[5];
    for (int i = 0; i < 5; i++) {
        W[i]   = (const float*)d_in[2 + 4 * i];
        bb[i]  = (const float*)d_in[3 + 4 * i];
        gg[i]  = (const float*)d_in[4 + 4 * i];
        beb[i] = (const float*)d_in[5 + 4 * i];
    }
    W[5] = (const float*)d_in[22];
    const float* bf = (const float*)d_in[23];
    float* out = (float*)d_out;

    // workspace layout (~34.5 MB, all 16B aligned)
    char* p = (char*)d_ws;
    __hip_bfloat16* hb   = (__hip_bfloat16*)p;  p += (size_t)N_PAD * D_H * 2;       // GEMM input
    __hip_bfloat16* tmpb = (__hip_bfloat16*)p;  p += (size_t)N_NODES * D_H * 2;     // GEMM output
    __hip_bfloat16* hagg = (__hip_bfloat16*)p;  p += (size_t)N_NODES * D_H * 2;     // aggregated
    __hip_bfloat16* Wt[6];
    int Kdim[6] = {256, 512, 512, 512, 512, 512};
    for (int i = 0; i < 6; i++) { Wt[i] = (__hip_bfloat16*)p; p += (size_t)D_H * Kdim[i] * 2; }
    float* dinv   = (float*)p;  p += N_NODES * 4;
    float* musum  = (float*)p;  p += D_H * 4;
    float* varsum = (float*)p;  p += D_H * 4;
    int* counts   = (int*)p;    p += N_NODES * 4;
    int* rowptr   = (int*)p;    p += (N_NODES + 1) * 4;
    int* cursor   = (int*)p;    p += N_NODES * 4;
    int* colidx   = (int*)p;

    // graph preprocessing
    k_init<<<(N_NODES + 255) / 256, 256, 0, stream>>>(dinv, counts);
    k_count<<<(N_EDGES + 255) / 256, 256, 0, stream>>>(ei, dinv, counts);
    k_dinv<<<(N_NODES + 255) / 256, 256, 0, stream>>>(dinv);
    k_scan<<<1, 1024, 0, stream>>>(counts, rowptr, cursor);
    k_fill<<<(N_EDGES + 255) / 256, 256, 0, stream>>>(ei, cursor, colidx);

    // weight convert+transpose, x convert
    WtPack wp;
    for (int i = 0; i < 6; i++) { wp.d[i].w = W[i]; wp.d[i].wt = Wt[i]; wp.d[i].di = Kdim[i]; }
    k_wt<<<dim3(16, 16, 6), 256, 0, stream>>>(wp);
    k_xcvt<<<1250, 256, 0, stream>>>(x, hb);

    dim3 ggrid(4, N_PAD / 128);
    for (int l = 0; l < 5; l++) {
        k_gemm_mfma<1><<<ggrid, 256, 0, stream>>>(hb, Wt[l], nullptr, tmpb, nullptr, Kdim[l]);
        k_aggregate<<<N_NODES / 4, 256, 0, stream>>>(tmpb, rowptr, colidx, dinv, bb[l], hagg, (l < 4) ? 1 : 0);
        k_zero<<<1, 1024, 0, stream>>>(musum);
        k_bnstats<<<100, 256, 0, stream>>>(hagg, musum, varsum);
        k_bnapply<<<2500, 256, 0, stream>>>(hagg, musum, varsum, gg[l], beb[l], hb);
    }
    k_gemm_mfma<0><<<ggrid, 256, 0, stream>>>(hb, Wt[5], bf, nullptr, out, 512);
}